// Round 1
// baseline (314.820 us; speedup 1.0000x reference)
//
#include <hip/hip_runtime.h>
#include <hip/hip_bf16.h>

typedef unsigned short u16;
typedef __attribute__((ext_vector_type(4))) float f32x4;
typedef __attribute__((ext_vector_type(8))) short short8;
typedef __attribute__((ext_vector_type(8))) unsigned short ushort8;

__device__ __forceinline__ u16 f2bf(float f) {
  union { float f; unsigned u; } v; v.f = f;
  unsigned r = v.u + 0x7fffu + ((v.u >> 16) & 1u);
  return (u16)(r >> 16);
}
__device__ __forceinline__ float b2f(u16 h) {
  union { unsigned u; float f; } v; v.u = ((unsigned)h) << 16;
  return v.f;
}
__device__ __forceinline__ f32x4 mfma16(short8 a, short8 b, f32x4 c) {
  return __builtin_amdgcn_mfma_f32_16x16x32_bf16(a, b, c, 0, 0, 0);
}

// ---------------- prep: fp32 -> bf16 convert ----------------
__global__ __launch_bounds__(256) void cvt_f32_bf16_k(const float* __restrict__ in,
                                                      u16* __restrict__ out, int n8) {
  int t = blockIdx.x * 256 + threadIdx.x;
  if (t >= n8) return;
  const float4* p = (const float4*)(in + (size_t)t * 8);
  float4 a = p[0], b = p[1];
  ushort8 o;
  o[0] = f2bf(a.x); o[1] = f2bf(a.y); o[2] = f2bf(a.z); o[3] = f2bf(a.w);
  o[4] = f2bf(b.x); o[5] = f2bf(b.y); o[6] = f2bf(b.z); o[7] = f2bf(b.w);
  *(ushort8*)(out + (size_t)t * 8) = o;
}

// ---------------- prep: transpose fp32 [R][C] -> bf16 [C][R] ----------------
__global__ __launch_bounds__(256) void transpose_f32_bf16_k(const float* __restrict__ in,
                                                            u16* __restrict__ out, int R, int C) {
  __shared__ float tile[32][33];
  int bc = blockIdx.x * 32, br = blockIdx.y * 32;
  int tx = threadIdx.x & 31, ty = threadIdx.x >> 5;
#pragma unroll
  for (int p = 0; p < 4; ++p)
    tile[ty + p * 8][tx] = in[(size_t)(br + ty + p * 8) * C + bc + tx];
  __syncthreads();
#pragma unroll
  for (int p = 0; p < 4; ++p)
    out[(size_t)(bc + ty + p * 8) * R + br + tx] = f2bf(tile[tx][ty + p * 8]);
}

// ---------------- GEMM (m97 structure): C[M][N] = A[M][K=1024] * Bt[N][K=1024]^T ----------------
// MODE 0: qkv epilogue (bias + scatter to Q/K/V [which][b][h][s][d] bf16)
// MODE 1: out epilogue (bias + fp32 store [m][n])
template <int MODE>
__global__ __launch_bounds__(256) void gemm_bt_k(const u16* __restrict__ A,
                                                 const u16* __restrict__ Bt,
                                                 const float* __restrict__ bias,
                                                 void* __restrict__ Cout) {
  __shared__ __align__(16) u16 As[128 * 32];
  __shared__ __align__(16) u16 Bs[128 * 32];
  const int tid = threadIdx.x, lane = tid & 63, w = tid >> 6;
  const int wr = w >> 1, wc = w & 1, g = lane >> 4, c16 = lane & 15;
  const int rowBase = blockIdx.y * 128, colBase = blockIdx.x * 128;
  f32x4 acc[4][4] = {};
  const int e0 = (w * 2 + 0) * 512 + lane * 8;
  const int e1 = (w * 2 + 1) * 512 + lane * 8;
  const u16* Ag0 = A + (size_t)(rowBase + (e0 >> 5)) * 1024 + (e0 & 31);
  const u16* Ag1 = A + (size_t)(rowBase + (e1 >> 5)) * 1024 + (e1 & 31);
  const u16* Bg0 = Bt + (size_t)(colBase + (e0 >> 5)) * 1024 + (e0 & 31);
  const u16* Bg1 = Bt + (size_t)(colBase + (e1 >> 5)) * 1024 + (e1 & 31);
  u16* As0 = As + (w * 2 + 0) * 512;
  u16* As1 = As + (w * 2 + 1) * 512;
  u16* Bs0 = Bs + (w * 2 + 0) * 512;
  u16* Bs1 = Bs + (w * 2 + 1) * 512;
  for (int k0 = 0; k0 < 1024; k0 += 32) {
    __builtin_amdgcn_global_load_lds((const __attribute__((address_space(1))) void*)(Ag0 + k0),
                                     (__attribute__((address_space(3))) void*)As0, 16, 0, 0);
    __builtin_amdgcn_global_load_lds((const __attribute__((address_space(1))) void*)(Ag1 + k0),
                                     (__attribute__((address_space(3))) void*)As1, 16, 0, 0);
    __builtin_amdgcn_global_load_lds((const __attribute__((address_space(1))) void*)(Bg0 + k0),
                                     (__attribute__((address_space(3))) void*)Bs0, 16, 0, 0);
    __builtin_amdgcn_global_load_lds((const __attribute__((address_space(1))) void*)(Bg1 + k0),
                                     (__attribute__((address_space(3))) void*)Bs1, 16, 0, 0);
    asm volatile("s_waitcnt vmcnt(0)" ::: "memory");
    __syncthreads();
    short8 af[4], bfr[4];
#pragma unroll
    for (int t = 0; t < 4; ++t)
      af[t] = *(const short8*)(As + ((wr * 64 + t * 16 + c16) * 32 + g * 8));
#pragma unroll
    for (int t = 0; t < 4; ++t)
      bfr[t] = *(const short8*)(Bs + ((wc * 64 + t * 16 + c16) * 32 + g * 8));
#pragma unroll
    for (int i = 0; i < 4; ++i)
#pragma unroll
      for (int j = 0; j < 4; ++j) acc[i][j] = mfma16(af[i], bfr[j], acc[i][j]);
    __syncthreads();
  }
#pragma unroll
  for (int i = 0; i < 4; ++i) {
    int mbase = rowBase + wr * 64 + i * 16 + 4 * g;
#pragma unroll
    for (int j = 0; j < 4; ++j) {
      int n = colBase + wc * 64 + j * 16 + c16;
      float bv = bias[n];
#pragma unroll
      for (int r = 0; r < 4; ++r) {
        float v = acc[i][j][r] + bv;
        int m = mbase + r;
        if (MODE == 0) {
          int which = n >> 10, hh = (n >> 6) & 15, d = n & 63;
          int bb = m >> 11, s = m & 2047;
          ((u16*)Cout)[((size_t)(((which * 2 + bb) * 16 + hh) * 2048 + s) << 6) + d] = f2bf(v);
        } else {
          ((float*)Cout)[(size_t)m * 1024 + n] = v;
        }
      }
    }
  }
}

// ---------------- RoPE in place on Q and K (first 2 "which" slabs of QKV ws) ----------------
__global__ __launch_bounds__(256) void rope_k(u16* __restrict__ qk, const float* __restrict__ cosT,
                                              const float* __restrict__ sinT, int npairs) {
  int p = blockIdx.x * 256 + threadIdx.x;
  if (p >= npairs) return;
  size_t E = (size_t)p * 2;
  int i = (int)((E >> 1) & 31);
  int s = (int)((E >> 6) & 2047);
  u16* ptr = qk + E;
  float xe = b2f(ptr[0]), xo = b2f(ptr[1]);
  float c = cosT[s * 32 + i], sn = sinT[s * 32 + i];
  float re = xe * c - xo * sn;
  float ro = xe * sn + xo * c;
  ptr[0] = f2bf(re);
  ptr[1] = f2bf(ro);
}

// ---------------- Flash attention (causal), 4 waves x 16 q-rows, k-tiles of 32 ----------------
__global__ __launch_bounds__(256) void attn_k(const u16* __restrict__ Qm, const u16* __restrict__ Km,
                                              const u16* __restrict__ Vm, u16* __restrict__ Om) {
  __shared__ __align__(16) u16 VtLds[64 * 40];   // V^T [hd][k], row stride 40 (80B, 16B-aligned)
  __shared__ __align__(16) u16 PLds[4 * 16 * 32]; // per-wave P [16 q][32 k]
  const int qblk = blockIdx.x, bh = blockIdx.y;
  const int b = bh >> 4, h = bh & 15;
  const u16* Qp = Qm + (size_t)bh * 2048 * 64;
  const u16* Kp = Km + (size_t)bh * 2048 * 64;
  const u16* Vp = Vm + (size_t)bh * 2048 * 64;
  const int tid = threadIdx.x, lane = tid & 63, w = tid >> 6;
  const int g = lane >> 4, c16 = lane & 15;
  const int qbase = qblk * 64;
  const int qrow = qbase + w * 16 + c16;
  const short8 qf0 = *(const short8*)(Qp + (size_t)qrow * 64 + g * 8);
  const short8 qf1 = *(const short8*)(Qp + (size_t)qrow * 64 + 32 + g * 8);
  float m_run[4] = {-1e30f, -1e30f, -1e30f, -1e30f};
  float l_run[4] = {0.f, 0.f, 0.f, 0.f};
  f32x4 acc[4] = {};
  const int nkt = qblk * 2 + 2;
  const int vk = tid >> 3, vh0 = (tid & 7) * 8;
  for (int kt = 0; kt < nkt; ++kt) {
    const int k0 = kt * 32;
    __syncthreads();
    {
      short8 vv = *(const short8*)(Vp + (size_t)(k0 + vk) * 64 + vh0);
#pragma unroll
      for (int e = 0; e < 8; ++e) VtLds[(vh0 + e) * 40 + vk] = (u16)vv[e];
    }
    __syncthreads();
    // scores: S[q][k] = Q[q][:] . K[k][:]
    f32x4 sc[2];
#pragma unroll
    for (int t = 0; t < 2; ++t) {
      const u16* kp = Kp + (size_t)(k0 + t * 16 + c16) * 64;
      short8 kf0 = *(const short8*)(kp + g * 8);
      short8 kf1 = *(const short8*)(kp + 32 + g * 8);
      f32x4 z = {};
      z = mfma16(qf0, kf0, z);
      z = mfma16(qf1, kf1, z);
      sc[t] = z;
    }
    float sv[2][4];
#pragma unroll
    for (int t = 0; t < 2; ++t) {
      int kg = k0 + t * 16 + c16;
#pragma unroll
      for (int j = 0; j < 4; ++j) {
        int qg = qbase + w * 16 + 4 * g + j;
        float v = sc[t][j] * 0.125f;
        sv[t][j] = (kg <= qg) ? v : -1e30f;
      }
    }
    float alpha[4], pv0[4], pv1[4];
#pragma unroll
    for (int j = 0; j < 4; ++j) {
      float rm = fmaxf(sv[0][j], sv[1][j]);
      rm = fmaxf(rm, __shfl_xor(rm, 1));
      rm = fmaxf(rm, __shfl_xor(rm, 2));
      rm = fmaxf(rm, __shfl_xor(rm, 4));
      rm = fmaxf(rm, __shfl_xor(rm, 8));
      float mn = fmaxf(m_run[j], rm);
      float a = __expf(m_run[j] - mn);
      float p0 = __expf(sv[0][j] - mn);
      float p1 = __expf(sv[1][j] - mn);
      float rs = p0 + p1;
      rs += __shfl_xor(rs, 1);
      rs += __shfl_xor(rs, 2);
      rs += __shfl_xor(rs, 4);
      rs += __shfl_xor(rs, 8);
      l_run[j] = l_run[j] * a + rs;
      m_run[j] = mn;
      alpha[j] = a;
      pv0[j] = p0;
      pv1[j] = p1;
    }
#pragma unroll
    for (int c = 0; c < 4; ++c)
#pragma unroll
      for (int j = 0; j < 4; ++j) acc[c][j] *= alpha[j];
    // P -> LDS (C-layout write), read back as MFMA A-fragment
#pragma unroll
    for (int j = 0; j < 4; ++j) {
      PLds[w * 512 + (4 * g + j) * 32 + 0 * 16 + c16] = f2bf(pv0[j]);
      PLds[w * 512 + (4 * g + j) * 32 + 1 * 16 + c16] = f2bf(pv1[j]);
    }
    asm volatile("s_waitcnt lgkmcnt(0)" ::: "memory");
    short8 pf = *(const short8*)(PLds + w * 512 + c16 * 32 + g * 8);
#pragma unroll
    for (int c = 0; c < 4; ++c) {
      short8 vf = *(const short8*)(VtLds + (16 * c + c16) * 40 + g * 8);
      acc[c] = mfma16(pf, vf, acc[c]);
    }
  }
#pragma unroll
  for (int c = 0; c < 4; ++c) {
#pragma unroll
    for (int j = 0; j < 4; ++j) {
      int q = qbase + w * 16 + 4 * g + j;
      int col = h * 64 + 16 * c + c16;
      float ov = acc[c][j] / l_run[j];
      Om[(size_t)(b * 2048 + q) * 1024 + col] = f2bf(ov);
    }
  }
}

extern "C" void kernel_launch(void* const* d_in, const int* in_sizes, int n_in,
                              void* d_out, int out_size, void* d_ws, size_t ws_size,
                              hipStream_t stream) {
  const float* x        = (const float*)d_in[0];
  const float* rope_cos = (const float*)d_in[1];
  const float* rope_sin = (const float*)d_in[2];
  const float* Wqkv     = (const float*)d_in[3];
  const float* bqkv     = (const float*)d_in[4];
  const float* Wout     = (const float*)d_in[5];
  const float* bout     = (const float*)d_in[6];
  float* out = (float*)d_out;
  char* ws = (char*)d_ws;

  u16* Xb      = (u16*)(ws);                  //  8,388,608 B  : x as bf16 [4096][1024]
  u16* WqkvT   = (u16*)(ws + 8388608);        //  6,291,456 B  : Wqkv^T bf16 [3072][1024]
  u16* WoutT   = (u16*)(ws + 14680064);       //  2,097,152 B  : Wout^T bf16 [1024][1024]
  u16* QKV     = (u16*)(ws + 16777216);       // 25,165,824 B  : [3][2][16][2048][64] bf16
  u16* AttnOut = (u16*)(ws + 41943040);       //  8,388,608 B  : [4096][1024] bf16

  // prep
  cvt_f32_bf16_k<<<dim3(2048), dim3(256), 0, stream>>>(x, Xb, 524288);
  transpose_f32_bf16_k<<<dim3(96, 32), dim3(256), 0, stream>>>(Wqkv, WqkvT, 1024, 3072);
  transpose_f32_bf16_k<<<dim3(32, 32), dim3(256), 0, stream>>>(Wout, WoutT, 1024, 1024);

  // QKV projection (bias fused, scatter to Q/K/V)
  gemm_bt_k<0><<<dim3(24, 32), dim3(256), 0, stream>>>(Xb, WqkvT, bqkv, (void*)QKV);

  // RoPE on Q and K slabs (first 2 * 4,194,304 elements of QKV)
  rope_k<<<dim3(16384), dim3(256), 0, stream>>>(QKV, rope_cos, rope_sin, 4194304);

  // attention
  u16* Qw = QKV;
  u16* Kw = QKV + (size_t)4194304;
  u16* Vw = QKV + (size_t)8388608;
  attn_k<<<dim3(32, 32), dim3(256), 0, stream>>>(Qw, Kw, Vw, AttnOut);

  // output projection
  gemm_bt_k<1><<<dim3(8, 32), dim3(256), 0, stream>>>(AttnOut, WoutT, bout, out);
}

// Round 2
// 166.868 us; speedup vs baseline: 1.8866x; 1.8866x over previous
//
#include <hip/hip_runtime.h>
#include <hip/hip_bf16.h>

typedef unsigned short u16;
typedef __attribute__((ext_vector_type(4))) float f32x4;
typedef __attribute__((ext_vector_type(8))) short short8;
typedef __attribute__((ext_vector_type(8))) unsigned short ushort8;

__device__ __forceinline__ u16 f2bf(float f) {
  union { float f; unsigned u; } v; v.f = f;
  unsigned r = v.u + 0x7fffu + ((v.u >> 16) & 1u);
  return (u16)(r >> 16);
}
__device__ __forceinline__ float b2f(u16 h) {
  union { unsigned u; float f; } v; v.u = ((unsigned)h) << 16;
  return v.f;
}
__device__ __forceinline__ f32x4 mfma16(short8 a, short8 b, f32x4 c) {
  return __builtin_amdgcn_mfma_f32_16x16x32_bf16(a, b, c, 0, 0, 0);
}
__device__ __forceinline__ unsigned cvtpk(float a, float b) {
  unsigned r;
  asm("v_cvt_pk_bf16_f32 %0, %1, %2" : "=v"(r) : "v"(a), "v"(b));
  return r;
}

// ---------------- prep: fp32 -> bf16 convert ----------------
__global__ __launch_bounds__(256) void cvt_f32_bf16_k(const float* __restrict__ in,
                                                      u16* __restrict__ out, int n8) {
  int t = blockIdx.x * 256 + threadIdx.x;
  if (t >= n8) return;
  const float4* p = (const float4*)(in + (size_t)t * 8);
  float4 a = p[0], b = p[1];
  ushort8 o;
  o[0] = f2bf(a.x); o[1] = f2bf(a.y); o[2] = f2bf(a.z); o[3] = f2bf(a.w);
  o[4] = f2bf(b.x); o[5] = f2bf(b.y); o[6] = f2bf(b.z); o[7] = f2bf(b.w);
  *(ushort8*)(out + (size_t)t * 8) = o;
}

// ---------------- prep: transpose fp32 [R][C] -> bf16 [C][R] ----------------
__global__ __launch_bounds__(256) void transpose_f32_bf16_k(const float* __restrict__ in,
                                                            u16* __restrict__ out, int R, int C) {
  __shared__ float tile[32][33];
  int bc = blockIdx.x * 32, br = blockIdx.y * 32;
  int tx = threadIdx.x & 31, ty = threadIdx.x >> 5;
#pragma unroll
  for (int p = 0; p < 4; ++p)
    tile[ty + p * 8][tx] = in[(size_t)(br + ty + p * 8) * C + bc + tx];
  __syncthreads();
#pragma unroll
  for (int p = 0; p < 4; ++p)
    out[(size_t)(bc + ty + p * 8) * R + br + tx] = f2bf(tile[tx][ty + p * 8]);
}

// ---------------- GEMM (m97 structure): C[M][N] = A[M][K=1024] * Bt[N][K=1024]^T ----------------
template <int MODE>
__global__ __launch_bounds__(256) void gemm_bt_k(const u16* __restrict__ A,
                                                 const u16* __restrict__ Bt,
                                                 const float* __restrict__ bias,
                                                 void* __restrict__ Cout) {
  __shared__ __align__(16) u16 As[128 * 32];
  __shared__ __align__(16) u16 Bs[128 * 32];
  const int tid = threadIdx.x, lane = tid & 63, w = tid >> 6;
  const int wr = w >> 1, wc = w & 1, g = lane >> 4, c16 = lane & 15;
  const int rowBase = blockIdx.y * 128, colBase = blockIdx.x * 128;
  f32x4 acc[4][4] = {};
  const int e0 = (w * 2 + 0) * 512 + lane * 8;
  const int e1 = (w * 2 + 1) * 512 + lane * 8;
  const u16* Ag0 = A + (size_t)(rowBase + (e0 >> 5)) * 1024 + (e0 & 31);
  const u16* Ag1 = A + (size_t)(rowBase + (e1 >> 5)) * 1024 + (e1 & 31);
  const u16* Bg0 = Bt + (size_t)(colBase + (e0 >> 5)) * 1024 + (e0 & 31);
  const u16* Bg1 = Bt + (size_t)(colBase + (e1 >> 5)) * 1024 + (e1 & 31);
  u16* As0 = As + (w * 2 + 0) * 512;
  u16* As1 = As + (w * 2 + 1) * 512;
  u16* Bs0 = Bs + (w * 2 + 0) * 512;
  u16* Bs1 = Bs + (w * 2 + 1) * 512;
  for (int k0 = 0; k0 < 1024; k0 += 32) {
    __builtin_amdgcn_global_load_lds((const __attribute__((address_space(1))) void*)(Ag0 + k0),
                                     (__attribute__((address_space(3))) void*)As0, 16, 0, 0);
    __builtin_amdgcn_global_load_lds((const __attribute__((address_space(1))) void*)(Ag1 + k0),
                                     (__attribute__((address_space(3))) void*)As1, 16, 0, 0);
    __builtin_amdgcn_global_load_lds((const __attribute__((address_space(1))) void*)(Bg0 + k0),
                                     (__attribute__((address_space(3))) void*)Bs0, 16, 0, 0);
    __builtin_amdgcn_global_load_lds((const __attribute__((address_space(1))) void*)(Bg1 + k0),
                                     (__attribute__((address_space(3))) void*)Bs1, 16, 0, 0);
    asm volatile("s_waitcnt vmcnt(0)" ::: "memory");
    __syncthreads();
    short8 af[4], bfr[4];
#pragma unroll
    for (int t = 0; t < 4; ++t)
      af[t] = *(const short8*)(As + ((wr * 64 + t * 16 + c16) * 32 + g * 8));
#pragma unroll
    for (int t = 0; t < 4; ++t)
      bfr[t] = *(const short8*)(Bs + ((wc * 64 + t * 16 + c16) * 32 + g * 8));
#pragma unroll
    for (int i = 0; i < 4; ++i)
#pragma unroll
      for (int j = 0; j < 4; ++j) acc[i][j] = mfma16(af[i], bfr[j], acc[i][j]);
    __syncthreads();
  }
#pragma unroll
  for (int i = 0; i < 4; ++i) {
    int mbase = rowBase + wr * 64 + i * 16 + 4 * g;
#pragma unroll
    for (int j = 0; j < 4; ++j) {
      int n = colBase + wc * 64 + j * 16 + c16;
      float bv = bias[n];
#pragma unroll
      for (int r = 0; r < 4; ++r) {
        float v = acc[i][j][r] + bv;
        int m = mbase + r;
        if (MODE == 0) {
          int which = n >> 10, hh = (n >> 6) & 15, d = n & 63;
          int bb = m >> 11, s = m & 2047;
          ((u16*)Cout)[((size_t)(((which * 2 + bb) * 16 + hh) * 2048 + s) << 6) + d] = f2bf(v);
        } else {
          ((float*)Cout)[(size_t)m * 1024 + n] = v;
        }
      }
    }
  }
}

// ---------------- RoPE in place on Q and K ----------------
__global__ __launch_bounds__(256) void rope_k(u16* __restrict__ qk, const float* __restrict__ cosT,
                                              const float* __restrict__ sinT, int npairs) {
  int p = blockIdx.x * 256 + threadIdx.x;
  if (p >= npairs) return;
  size_t E = (size_t)p * 2;
  int i = (int)((E >> 1) & 31);
  int s = (int)((E >> 6) & 2047);
  u16* ptr = qk + E;
  float xe = b2f(ptr[0]), xo = b2f(ptr[1]);
  float c = cosT[s * 32 + i], sn = sinT[s * 32 + i];
  ptr[0] = f2bf(xe * c - xo * sn);
  ptr[1] = f2bf(xe * sn + xo * c);
}

// ---------------- V [bh][s][64] -> Vt [bh][64][s] (bf16) ----------------
__global__ __launch_bounds__(256) void vtrans_k(const u16* __restrict__ V, u16* __restrict__ Vt) {
  __shared__ u16 t[64][72];
  const int bh = blockIdx.y, s0 = blockIdx.x * 64;
  const u16* src = V + ((size_t)bh << 17);
  u16* dst = Vt + ((size_t)bh << 17);
  const int r = threadIdx.x >> 2, c0 = (threadIdx.x & 3) * 16;
  *(short8*)&t[r][c0] = *(const short8*)(src + (size_t)(s0 + r) * 64 + c0);
  *(short8*)&t[r][c0 + 8] = *(const short8*)(src + (size_t)(s0 + r) * 64 + c0 + 8);
  __syncthreads();
  const int d = threadIdx.x >> 2, sc0 = (threadIdx.x & 3) * 16;
  ushort8 o0, o1;
#pragma unroll
  for (int e = 0; e < 8; ++e) { o0[e] = t[sc0 + e][d]; o1[e] = t[sc0 + 8 + e][d]; }
  *(ushort8*)(dst + (size_t)d * 2048 + s0 + sc0) = o0;
  *(ushort8*)(dst + (size_t)d * 2048 + s0 + sc0 + 8) = o1;
}

// ---------------- Flash attention: 64-row macro-tile, 4 waves, swapped QK^T ----------------
// grid 1024 blocks: flat -> (bh, mt) with XCD grouping + LPT (longest first).
// Per block: K tile + Vt tile staged in LDS (double-buffered, XOR-swizzled via
// pre-swizzled global source for global_load_lds), KVBLK = 64.
__global__ __launch_bounds__(256, 4) void attn2_k(const u16* __restrict__ Qm,
                                                  const u16* __restrict__ Km,
                                                  const u16* __restrict__ Vtm,
                                                  u16* __restrict__ Om) {
  __shared__ __align__(16) u16 Klds[2][4096];
  __shared__ __align__(16) u16 Vtlds[2][4096];
  __shared__ __align__(16) u16 Plds[4][1024];

  const int flat = blockIdx.x;
  const int bh = (flat & 7) | ((flat >> 8) << 3);   // 4 heads per XCD stream
  const int mt = 31 - ((flat >> 3) & 31);           // LPT: longest macro-tile first
  const int b = bh >> 4, h = bh & 15;

  const u16* Qp = Qm + ((size_t)bh << 17);
  const u16* Kp = Km + ((size_t)bh << 17);
  const u16* Vtp = Vtm + ((size_t)bh << 17);

  const int tid = threadIdx.x, lane = tid & 63, w = tid >> 6;
  const int g = lane >> 4, c16 = lane & 15;
  const int qb = mt * 64 + w * 16;

  // Q fragments (B-operand): lane holds Q[qb+c16][8g..8g+7] and [32+8g..]
  const u16* qrow = Qp + ((size_t)(qb + c16) << 6);
  const short8 qf0 = *(const short8*)(qrow + g * 8);
  const short8 qf1 = *(const short8*)(qrow + 32 + g * 8);

  float m_run = -1e30f, l_run = 0.f;
  f32x4 acc[4] = {};
  u16* Pw = &Plds[w][0];

  auto stage = [&](int buf, int k0) {
#pragma unroll
    for (int j = 0; j < 2; ++j) {
      const int reg = w * 2 + j;
      const int sr = reg * 8 + (lane >> 3);      // row (kv for K, d for Vt)
      const int sb = lane & 7;                   // 16B block within row
      const int sw = 8 * (sb ^ (sr & 7));        // pre-swizzled source column
      const u16* ksrc = Kp + ((size_t)(k0 + sr) << 6) + sw;
      __builtin_amdgcn_global_load_lds(
          (const __attribute__((address_space(1))) void*)ksrc,
          (__attribute__((address_space(3))) void*)(&Klds[buf][reg * 512]), 16, 0, 0);
      const u16* vsrc = Vtp + ((size_t)sr << 11) + k0 + sw;
      __builtin_amdgcn_global_load_lds(
          (const __attribute__((address_space(1))) void*)vsrc,
          (__attribute__((address_space(3))) void*)(&Vtlds[buf][reg * 512]), 16, 0, 0);
    }
  };

  stage(0, 0);
  asm volatile("s_waitcnt vmcnt(0)" ::: "memory");
  __syncthreads();

  for (int kt = 0; kt <= mt; ++kt) {
    const int cur = kt & 1;
    if (kt < mt) stage(cur ^ 1, (kt + 1) * 64);

    // ---- QK^T swapped: sc[t][r] = S[kv = 64kt+16t+4g+r][q = qb+c16]
    const u16* Kb = &Klds[cur][0];
    f32x4 sc[4];
#pragma unroll
    for (int t = 0; t < 4; ++t) {
      const int krow = 16 * t + c16;
      const int swz = krow & 7;
      short8 kf0 = *(const short8*)(Kb + krow * 64 + ((g ^ swz) * 8));
      short8 kf1 = *(const short8*)(Kb + krow * 64 + (((4 | g) ^ swz) * 8));
      f32x4 z = {0.f, 0.f, 0.f, 0.f};
      z = mfma16(kf0, qf0, z);
      z = mfma16(kf1, qf1, z);
      sc[t] = z;
    }

    // ---- mask (last tile only) + online softmax, per-lane row q = qb+c16
    float sv[4][4];
    if (kt == mt) {
      const int qloc = 16 * w + c16;
#pragma unroll
      for (int t = 0; t < 4; ++t)
#pragma unroll
        for (int r = 0; r < 4; ++r)
          sv[t][r] = (16 * t + 4 * g + r <= qloc) ? sc[t][r] : -1e30f;
    } else {
#pragma unroll
      for (int t = 0; t < 4; ++t)
#pragma unroll
        for (int r = 0; r < 4; ++r) sv[t][r] = sc[t][r];
    }
    float rm = sv[0][0];
#pragma unroll
    for (int t = 0; t < 4; ++t)
#pragma unroll
      for (int r = 0; r < 4; ++r) rm = fmaxf(rm, sv[t][r]);
    rm = fmaxf(rm, __shfl_xor(rm, 16));
    rm = fmaxf(rm, __shfl_xor(rm, 32));
    const float mn = fmaxf(m_run, rm);
    const float alpha = __expf((m_run - mn) * 0.125f);
    float p[4][4];
    float rs = 0.f;
#pragma unroll
    for (int t = 0; t < 4; ++t)
#pragma unroll
      for (int r = 0; r < 4; ++r) {
        float pv = __expf((sv[t][r] - mn) * 0.125f);
        p[t][r] = pv;
        rs += pv;
      }
    rs += __shfl_xor(rs, 16);
    rs += __shfl_xor(rs, 32);
    l_run = l_run * alpha + rs;
    m_run = mn;

    // ---- P -> LDS (4 swizzled b64 writes of cvt_pk pairs)
#pragma unroll
    for (int t = 0; t < 4; ++t) {
      uint2 dw;
      dw.x = cvtpk(p[t][0], p[t][1]);
      dw.y = cvtpk(p[t][2], p[t][3]);
      *(uint2*)(Pw + c16 * 64 + ((16 * t + 4 * g) ^ ((c16 & 7) << 3))) = dw;
    }
    // rescale acc rows (alpha broadcast: row 4g+r lives at lane 4g+r)
    float ar[4];
#pragma unroll
    for (int r = 0; r < 4; ++r) ar[r] = __shfl(alpha, 4 * g + r);
#pragma unroll
    for (int c = 0; c < 4; ++c)
#pragma unroll
      for (int r = 0; r < 4; ++r) acc[c][r] *= ar[r];

    asm volatile("s_waitcnt lgkmcnt(0)" ::: "memory");
    const int pswz = c16 & 7;
    const short8 pf0 = *(const short8*)(Pw + c16 * 64 + ((g ^ pswz) * 8));
    const short8 pf1 = *(const short8*)(Pw + c16 * 64 + (((4 | g) ^ pswz) * 8));

    // ---- PV: acc[c] += P[q][kv] * V[kv][16c+c16]
    const u16* Vb = &Vtlds[cur][0];
#pragma unroll
    for (int c = 0; c < 4; ++c) {
      const int vrow = 16 * c + c16;
      const int vswz = vrow & 7;
      short8 vf0 = *(const short8*)(Vb + vrow * 64 + ((g ^ vswz) * 8));
      short8 vf1 = *(const short8*)(Vb + vrow * 64 + (((4 | g) ^ vswz) * 8));
      acc[c] = mfma16(pf0, vf0, acc[c]);
      acc[c] = mfma16(pf1, vf1, acc[c]);
    }

    asm volatile("s_waitcnt vmcnt(0)" ::: "memory");
    __syncthreads();
  }

  // ---- epilogue: divide by l (broadcast) and store
  float lr[4];
#pragma unroll
  for (int r = 0; r < 4; ++r) lr[r] = 1.0f / __shfl(l_run, 4 * g + r);
#pragma unroll
  for (int c = 0; c < 4; ++c)
#pragma unroll
    for (int r = 0; r < 4; ++r) {
      const int q = qb + 4 * g + r;
      Om[((size_t)(b * 2048 + q) << 10) + h * 64 + 16 * c + c16] = f2bf(acc[c][r] * lr[r]);
    }
}

extern "C" void kernel_launch(void* const* d_in, const int* in_sizes, int n_in,
                              void* d_out, int out_size, void* d_ws, size_t ws_size,
                              hipStream_t stream) {
  const float* x        = (const float*)d_in[0];
  const float* rope_cos = (const float*)d_in[1];
  const float* rope_sin = (const float*)d_in[2];
  const float* Wqkv     = (const float*)d_in[3];
  const float* bqkv     = (const float*)d_in[4];
  const float* Wout     = (const float*)d_in[5];
  const float* bout     = (const float*)d_in[6];
  float* out = (float*)d_out;
  char* ws = (char*)d_ws;

  u16* Xb      = (u16*)(ws);                  //  8,388,608 B : x bf16 [4096][1024]
  u16* WqkvT   = (u16*)(ws + 8388608);        //  6,291,456 B : Wqkv^T bf16
  u16* WoutT   = (u16*)(ws + 14680064);       //  2,097,152 B : Wout^T bf16
  u16* QKV     = (u16*)(ws + 16777216);       // 25,165,824 B : [3][2][16][2048][64]
  u16* AttnOut = (u16*)(ws + 41943040);       //  8,388,608 B : [4096][1024] bf16
  u16* Vt      = (u16*)(ws + 50331648);       //  8,388,608 B : [32][64][2048] bf16

  cvt_f32_bf16_k<<<dim3(2048), dim3(256), 0, stream>>>(x, Xb, 524288);
  transpose_f32_bf16_k<<<dim3(96, 32), dim3(256), 0, stream>>>(Wqkv, WqkvT, 1024, 3072);
  transpose_f32_bf16_k<<<dim3(32, 32), dim3(256), 0, stream>>>(Wout, WoutT, 1024, 1024);

  gemm_bt_k<0><<<dim3(24, 32), dim3(256), 0, stream>>>(Xb, WqkvT, bqkv, (void*)QKV);

  rope_k<<<dim3(16384), dim3(256), 0, stream>>>(QKV, rope_cos, rope_sin, 4194304);

  u16* Qw = QKV;
  u16* Kw = QKV + (size_t)4194304;
  u16* Vw = QKV + (size_t)8388608;
  vtrans_k<<<dim3(32, 32), dim3(256), 0, stream>>>(Vw, Vt);
  attn2_k<<<dim3(1024), dim3(256), 0, stream>>>(Qw, Kw, Vt, AttnOut);

  gemm_bt_k<1><<<dim3(8, 32), dim3(256), 0, stream>>>(AttnOut, WoutT, bout, out);
}